// Round 4
// baseline (67.798 us; speedup 1.0000x reference)
//
#include <hip/hip_runtime.h>
#include <hip/hip_bf16.h>

#define A_ 8
#define B_ 256
#define I_ 256
#define J_ 256
#define K_ 256

typedef __attribute__((ext_vector_type(8))) short short8_t;
typedef __attribute__((ext_vector_type(4))) float f32x4_t;

static __device__ __forceinline__ uint pack2bf(float a, float b) {
  float2 f2; f2.x = a; f2.y = b;
  __hip_bfloat162 h2 = __float22bfloat162_rn(f2);
  uint r;
  __builtin_memcpy(&r, &h2, 4);
  return r;
}

static __device__ __forceinline__ float bits2f(uint u) {
  float f;
  __builtin_memcpy(&f, &u, 4);
  return f;
}

// ---------------------------------------------------------------------------
// Prepass: cbf[b][j] = bf16(c[b][j])
// ---------------------------------------------------------------------------
__global__ __launch_bounds__(256) void prepass_kernel(
    const float* __restrict__ c, ushort* __restrict__ cbf) {
  const int idx = blockIdx.x * 256 + threadIdx.x;
  const f32x4_t v = *reinterpret_cast<const f32x4_t*>(c + (size_t)idx * 4);
  uint2 r;
  r.x = pack2bf(v[0], v[1]);
  r.y = pack2bf(v[2], v[3]);
  *reinterpret_cast<uint2*>(cbf + (size_t)idx * 4) = r;
}

// ---------------------------------------------------------------------------
// Pass 1: u[b][i][k] = sum_j c[b][j] * w[i][j][k]
// u stored bf16 in layout u2[b>>2][i][k][b&3]  (so the 4 consecutive-b accs
// of one MFMA fragment store as ONE contiguous 8B uint2 -> 4x fewer stores).
// Grid (i, k-quarter) = (256,4). 256 threads = 4 waves, each 64(b) x 64(k).
// A (cbf) frags direct from global (L2-hot), ping-pong prefetched.
// B (w) micro-tile 2j x 4k per thread via dwordx4, reg-transpose, b32 LDS
// writes into Bt[k][j]; b128 frag reads. One barrier per j-step.
// ---------------------------------------------------------------------------
#define BK 32
#define LDK 40  // Bt row length in halves (80B, 16B-aligned; 2-way banks)

__global__ __launch_bounds__(256, 2) void pass1_kernel(
    const ushort* __restrict__ cbf, const float* __restrict__ w,
    ushort* __restrict__ u2) {
  const int i    = blockIdx.x;
  const int k0   = blockIdx.y * 64;
  const int tid  = threadIdx.x;
  const int lane = tid & 63;
  const int wave = tid >> 6;   // b-quadrant (0..3)
  const int lrow = lane & 15;
  const int lhi  = lane >> 4;  // 0..3

  __shared__ ushort Bt[2][64][LDK];  // [k-local][j-local], double-buffered

  const float* wi = w + (size_t)i * (J_ * K_) + k0;

  // B staging: thread = (j-pair, k-quad) micro-tile
  const int jp = tid & 15;  // 0..15 -> j-local = jp*2 + jj
  const int kq = tid >> 4;  // 0..15 -> k-local = kq*4 + kk

  // A frag row base (direct-from-global)
  const int arow = wave * 64 + lrow;

  f32x4_t acc[4][4];
#pragma unroll
  for (int m = 0; m < 4; m++)
#pragma unroll
    for (int n = 0; n < 4; n++) acc[m][n] = (f32x4_t)(0.0f);

  f32x4_t  bv[2][2];   // [buf][jj] : 4 consecutive k of one j-row
  short8_t afr[2][4];

#define LOADB(p, j0)                                                        \
  {                                                                         \
    _Pragma("unroll") for (int jj = 0; jj < 2; jj++)                        \
        bv[p][jj] = *reinterpret_cast<const f32x4_t*>(                      \
            wi + (size_t)((j0) + jp * 2 + jj) * K_ + kq * 4);               \
  }
#define LOADA(p, j0)                                                        \
  {                                                                         \
    _Pragma("unroll") for (int m = 0; m < 4; m++)                           \
        afr[p][m] = *reinterpret_cast<const short8_t*>(                     \
            cbf + (size_t)(arow + m * 16) * J_ + (j0) + lhi * 8);           \
  }
#define STOREB(buf, p)                                                      \
  {                                                                         \
    _Pragma("unroll") for (int kk = 0; kk < 4; kk++)                        \
        *reinterpret_cast<uint*>(&Bt[buf][kq * 4 + kk][jp * 2]) =           \
            pack2bf(bv[p][0][kk], bv[p][1][kk]);                            \
  }

  LOADB(0, 0);
  LOADA(0, 0);
  STOREB(0, 0);
  __syncthreads();

#pragma unroll
  for (int t = 0; t < 8; ++t) {
    const int cur = t & 1;
    const int nxt = cur ^ 1;
    if (t < 7) {
      LOADB(nxt, (t + 1) * BK);
      LOADA(nxt, (t + 1) * BK);
    }
    short8_t bfr[4];
#pragma unroll
    for (int n = 0; n < 4; n++)
      bfr[n] = *reinterpret_cast<const short8_t*>(
          &Bt[cur][n * 16 + lrow][lhi * 8]);
#pragma unroll
    for (int m = 0; m < 4; m++)
#pragma unroll
      for (int n = 0; n < 4; n++)
        acc[m][n] = __builtin_amdgcn_mfma_f32_16x16x32_bf16(
            afr[cur][m], bfr[n], acc[m][n], 0, 0, 0);
    if (t < 7) STOREB(nxt, nxt);
    __syncthreads();
  }

  // epilogue: u2[b4][i][k][rb], rb = acc reg index (4 consecutive b)
#pragma unroll
  for (int m = 0; m < 4; m++) {
    const int b4 = wave * 16 + m * 4 + lhi;
#pragma unroll
    for (int n = 0; n < 4; n++) {
      const int kc = k0 + n * 16 + lrow;
      uint2 val;
      val.x = pack2bf(acc[m][n][0], acc[m][n][1]);
      val.y = pack2bf(acc[m][n][2], acc[m][n][3]);
      *reinterpret_cast<uint2*>(
          u2 + (((size_t)b4 * I_ + i) * K_ + kc) * 4) = val;
    }
  }
#undef LOADB
#undef LOADA
#undef STOREB
}

// ---------------------------------------------------------------------------
// Pass 2: out[a][b][k] = sum_i s[a][b][i] * u[b][i][k] + bias[k]
// Grid (b4, k-quarter) = (64,4). Thread = (kl 0..63, ig 0..3).
// Per i: one 8B u2 load (4 rb) + broadcast LDS s reads (fp32), 32 FMA.
// LDS reduce over the 4 i-groups.
// ---------------------------------------------------------------------------
__global__ __launch_bounds__(256) void pass2_kernel(
    const float* __restrict__ s, const ushort* __restrict__ u2,
    const float* __restrict__ bias, float* __restrict__ out) {
  const int b4  = blockIdx.x;
  const int kq  = blockIdx.y;
  const int tid = threadIdx.x;
  const int kl  = tid & 63;
  const int ig  = tid >> 6;
  const int k   = kq * 64 + kl;

  __shared__ float smem[256 * 32];  // 32KB: s_l[i][rb][a], then red[ig][kl][p]

  // stage s -> smem[i*32 + rb*8 + a]
  {
    const int pair = tid >> 3;       // 0..31
    const int a    = pair >> 2;
    const int rb   = pair & 3;
    const int ic   = (tid & 7) * 32;
    const float* src = s + ((size_t)a * B_ + b4 * 4 + rb) * I_ + ic;
#pragma unroll
    for (int q = 0; q < 8; q++) {
      const f32x4_t v = *reinterpret_cast<const f32x4_t*>(src + q * 4);
#pragma unroll
      for (int e = 0; e < 4; e++)
        smem[(ic + q * 4 + e) * 32 + rb * 8 + a] = v[e];
    }
  }
  __syncthreads();

  float acc[8][4];
#pragma unroll
  for (int a = 0; a < 8; a++)
#pragma unroll
    for (int rb = 0; rb < 4; rb++) acc[a][rb] = 0.0f;

  const ushort* ubase = u2 + (((size_t)b4 * I_ + ig * 64) * K_ + k) * 4;
#pragma unroll 4
  for (int ii = 0; ii < 64; ++ii) {
    const uint2 uv =
        *reinterpret_cast<const uint2*>(ubase + (size_t)ii * (K_ * 4));
    float uf[4];
    uf[0] = bits2f(uv.x << 16);
    uf[1] = bits2f(uv.x & 0xffff0000u);
    uf[2] = bits2f(uv.y << 16);
    uf[3] = bits2f(uv.y & 0xffff0000u);
    const float* srow = &smem[(ig * 64 + ii) * 32];
#pragma unroll
    for (int rb = 0; rb < 4; rb++) {
      const f32x4_t s0 = *reinterpret_cast<const f32x4_t*>(srow + rb * 8);
      const f32x4_t s1 = *reinterpret_cast<const f32x4_t*>(srow + rb * 8 + 4);
#pragma unroll
      for (int e = 0; e < 4; e++) {
        acc[e][rb]     += s0[e] * uf[rb];
        acc[4 + e][rb] += s1[e] * uf[rb];
      }
    }
  }
  __syncthreads();  // done reading s_l; reuse smem as red

  // red[ig][kl][p], p = a*4+rb
  {
    float* dst = &smem[(ig * 64 + kl) * 32];
#pragma unroll
    for (int a = 0; a < 8; a++) {
      f32x4_t v;
#pragma unroll
      for (int rb = 0; rb < 4; rb++) v[rb] = acc[a][rb];
      *reinterpret_cast<f32x4_t*>(dst + a * 4) = v;
    }
  }
  __syncthreads();

  {
    const int kl2 = tid & 63;
    const int pr  = tid >> 6;  // 0..3 -> pairs pr*8..pr*8+7
    const int kk  = kq * 64 + kl2;
    const float bk = bias[kk];
#pragma unroll
    for (int q = 0; q < 8; q++) {
      const int p = pr * 8 + q;
      float sum = 0.0f;
#pragma unroll
      for (int g = 0; g < 4; g++) sum += smem[((g * 64) + kl2) * 32 + p];
      const int a  = p >> 2;
      const int rb = p & 3;
      out[((size_t)a * B_ + b4 * 4 + rb) * K_ + kk] = sum + bk;
    }
  }
}

// ---------------------------------------------------------------------------
// Fallback (slow but correct, fp32): used only if workspace is too small.
// ---------------------------------------------------------------------------
__global__ __launch_bounds__(256) void fallback_kernel(
    const float* __restrict__ s, const float* __restrict__ cmat,
    const float* __restrict__ w, const float* __restrict__ bias,
    float* __restrict__ out) {
  const int b = blockIdx.x;
  const int k = threadIdx.x;
  __shared__ float c_l[J_];
  __shared__ float s_l[A_][I_];
  for (int idx = threadIdx.x; idx < J_; idx += 256) c_l[idx] = cmat[(size_t)b * J_ + idx];
  for (int idx = threadIdx.x; idx < A_ * I_; idx += 256) {
    const int a = idx >> 8;
    const int i = idx & 255;
    s_l[a][i] = s[(size_t)a * (B_ * I_) + (size_t)b * I_ + i];
  }
  __syncthreads();
  float acc[A_];
#pragma unroll
  for (int a = 0; a < A_; a++) acc[a] = 0.0f;
  for (int i = 0; i < I_; i++) {
    const float* wrow = w + (size_t)i * (J_ * K_) + k;
    float inner = 0.0f;
    for (int j = 0; j < J_; j++) inner += c_l[j] * wrow[(size_t)j * K_];
#pragma unroll
    for (int a = 0; a < A_; a++) acc[a] += s_l[a][i] * inner;
  }
#pragma unroll
  for (int a = 0; a < A_; a++)
    out[((size_t)a * B_ + b) * K_ + k] = acc[a] + bias[k];
}

extern "C" void kernel_launch(void* const* d_in, const int* in_sizes, int n_in,
                              void* d_out, int out_size, void* d_ws, size_t ws_size,
                              hipStream_t stream) {
  const float* s    = (const float*)d_in[0];  // (A,B,I)
  const float* cmat = (const float*)d_in[1];  // (B,J)
  const float* w    = (const float*)d_in[2];  // (I,J,K)
  const float* bias = (const float*)d_in[3];  // (K,)
  float* out = (float*)d_out;

  const size_t u_elems = (size_t)B_ * I_ * K_;
  const size_t need = u_elems * sizeof(ushort) + (size_t)B_ * J_ * sizeof(ushort);
  if (ws_size >= need) {
    ushort* u2  = (ushort*)d_ws;
    ushort* cbf = (ushort*)d_ws + u_elems;
    prepass_kernel<<<dim3((B_ * J_) / (256 * 4)), dim3(256), 0, stream>>>(cmat, cbf);
    pass1_kernel<<<dim3(I_, 4), dim3(256), 0, stream>>>(cbf, w, u2);
    pass2_kernel<<<dim3(64, 4), dim3(256), 0, stream>>>(s, u2, bias, out);
  } else {
    fallback_kernel<<<dim3(B_), dim3(256), 0, stream>>>(s, cmat, w, bias, out);
  }
}